// Round 11
// baseline (90.687 us; speedup 1.0000x reference)
//
#include <hip/hip_runtime.h>
#include <hip/hip_bf16.h>

// Problem constants
#define BB 32
#define SS 256
#define DD 300
#define PDD 32
#define MM 66
#define FF 398      // D + PD + M
#define HH 6
#define G4 24       // 4*H
#define AA 12
#define L2E 1.4426950408889634f

__device__ __forceinline__ float fast_rcp(float x) { return __builtin_amdgcn_rcpf(x); }
__device__ __forceinline__ float fast_tanh(float x) {
    return 1.f - 2.f * fast_rcp(__expf(2.f * x) + 1.f);
}
__device__ __forceinline__ float bcast_lane(float x, int l) {
    return __int_as_float(__builtin_amdgcn_readlane(__float_as_int(x), l));
}
template<int CTRL>
__device__ __forceinline__ float quad_bcast(float v) {
    return __int_as_float(__builtin_amdgcn_mov_dpp(__float_as_int(v), CTRL, 0xf, 0xf, true));
}

// -------------------------------------------------------------------------
// Kernel 1 (v5, unchanged from R9): fused embed+concat+projection.
// Block = 32 positions, 256 thr, grid 256 (1 block/CU). Feats transposed in
// LDS; all of W in LDS. Epilogue folds bias + the lstm's +-log2e prescale.
// -------------------------------------------------------------------------
#define EPB 32
__global__ __launch_bounds__(256) void k_embed_proj(
    const int* __restrict__ words, const int* __restrict__ pos,
    const float* __restrict__ morph, const float* __restrict__ wtab,
    const float* __restrict__ ptab,
    const float* __restrict__ Wxf, const float* __restrict__ bfv,
    const float* __restrict__ Wxb, const float* __restrict__ bbv,
    float* __restrict__ xgf, float* __restrict__ xgb)
{
    __shared__ float4 sF[100][33];      // 52.8 KB
    __shared__ float4 sW[48 * 100];     // 76.8 KB
    int t  = threadIdx.x;
    int p0 = blockIdx.x * EPB;

    for (int idx = t; idx < EPB * 75; idx += 256) {
        int p = idx / 75, q = idx % 75;
        sF[q][p] = *(const float4*)(wtab + (size_t)words[p0 + p] * DD + 4 * q);
    }
    {
        int idx = t;                    // EPB*8 = 256 exactly
        int p = idx / 8, q = idx % 8;
        sF[75 + q][p] = *(const float4*)(ptab + pos[p0 + p] * PDD + 4 * q);
    }
    for (int idx = t; idx < EPB * 17; idx += 256) {
        int p = idx / 17, mq = idx % 17;
        const float2* ms = (const float2*)(morph + (size_t)(p0 + p) * MM);
        float2 lo = ms[2 * mq];
        float2 hi = (mq < 16) ? ms[2 * mq + 1] : make_float2(0.f, 0.f);
        sF[83 + mq][p] = make_float4(lo.x, lo.y, hi.x, hi.y);
    }
    {
        float* sWf = (float*)sW;
        for (int idx = t; idx < FF * G4; idx += 256) {
            int k = idx / G4, j = idx % G4;
            sWf[j * 400 + k]        = Wxf[idx];
            sWf[(24 + j) * 400 + k] = Wxb[idx];
        }
        if (t < 2 * G4) {
            int j = t >> 1, k = 398 + (t & 1);
            sWf[j * 400 + k] = 0.f; sWf[(24 + j) * 400 + k] = 0.f;
        }
    }
    __syncthreads();

    int lane = t & 63, w = t >> 6;
    int p    = lane & 31;
    int cg   = w * 2 + (lane >> 5);
    int dir  = cg >> 2;
    int tg   = cg & 3;
    int j0   = tg * 6;
    const float4* wc = sW + (dir * 24 + j0) * 100;

    float a0 = 0.f, a1 = 0.f, a2 = 0.f, a3 = 0.f, a4 = 0.f, a5 = 0.f;
    #pragma unroll 4
    for (int q = 0; q < 100; ++q) {
        float4 f = sF[q][p];
        float4 w0 = wc[0 * 100 + q], w1 = wc[1 * 100 + q], w2 = wc[2 * 100 + q];
        float4 w3 = wc[3 * 100 + q], w4 = wc[4 * 100 + q], w5 = wc[5 * 100 + q];
        a0 = fmaf(f.x, w0.x, a0); a0 = fmaf(f.y, w0.y, a0);
        a0 = fmaf(f.z, w0.z, a0); a0 = fmaf(f.w, w0.w, a0);
        a1 = fmaf(f.x, w1.x, a1); a1 = fmaf(f.y, w1.y, a1);
        a1 = fmaf(f.z, w1.z, a1); a1 = fmaf(f.w, w1.w, a1);
        a2 = fmaf(f.x, w2.x, a2); a2 = fmaf(f.y, w2.y, a2);
        a2 = fmaf(f.z, w2.z, a2); a2 = fmaf(f.w, w2.w, a2);
        a3 = fmaf(f.x, w3.x, a3); a3 = fmaf(f.y, w3.y, a3);
        a3 = fmaf(f.z, w3.z, a3); a3 = fmaf(f.w, w3.w, a3);
        a4 = fmaf(f.x, w4.x, a4); a4 = fmaf(f.y, w4.y, a4);
        a4 = fmaf(f.z, w4.z, a4); a4 = fmaf(f.w, w4.w, a4);
        a5 = fmaf(f.x, w5.x, a5); a5 = fmaf(f.y, w5.y, a5);
        a5 = fmaf(f.z, w5.z, a5); a5 = fmaf(f.w, w5.w, a5);
    }

    float kk = (tg == 2) ? 2.f * L2E : -L2E;
    const float* bias = dir ? bbv : bfv;
    float* o = (dir ? xgb : xgf) + (size_t)(p0 + p) * G4 + j0;
    o[0] = (a0 + bias[j0 + 0]) * kk; o[1] = (a1 + bias[j0 + 1]) * kk;
    o[2] = (a2 + bias[j0 + 2]) * kk; o[3] = (a3 + bias[j0 + 3]) * kk;
    o[4] = (a4 + bias[j0 + 4]) * kk; o[5] = (a5 + bias[j0 + 5]) * kk;
}

// -------------------------------------------------------------------------
// Kernel 2 (v11): LSTM recurrence, TWO interleaved chains per wave.
// Block q (32 blocks): dir = q>>4, chains bA = q&15 and bB = bA+16 (same
// dir -> shared Wh). Both chains live in the same lanes with separate
// registers; their independent dependency chains interleave, so one chain's
// latency bubbles (exp2/rcp/readlane/ds_read) are filled by the other's
// instructions. Gate-lane layout + DPP quad gathers as in v9.
// -------------------------------------------------------------------------
__global__ __launch_bounds__(64) void k_lstm(
    const float* __restrict__ xgf, const float* __restrict__ xgb,
    const float* __restrict__ Whf, const float* __restrict__ Whb,
    float* __restrict__ repr)
{
    __shared__ float sxgA[(SS + 8) * G4];   // 25.3 KB each, 8 zero guard rows
    __shared__ float sxgB[(SS + 8) * G4];
    __shared__ float hbufA[SS * HH];
    __shared__ float hbufB[SS * HH];
    int q   = blockIdx.x;                   // 0..31
    int dir = q >> 4;
    int bA  = q & 15;
    int bB  = bA + 16;
    int lane = threadIdx.x;

    const float* xgbase = dir ? xgb : xgf;
    const float* Wh = dir ? Whb : Whf;

    // stage both chains' xg -> LDS (pure copy; reverse rows for bwd)
    {
        const float4* srcA = (const float4*)(xgbase + (size_t)bA * SS * G4);
        const float4* srcB = (const float4*)(xgbase + (size_t)bB * SS * G4);
        float4* dA = (float4*)sxgA;
        float4* dB = (float4*)sxgB;
        #pragma unroll
        for (int u = 0; u < 24; ++u) {
            int d = lane + u * 64;          // float4 index 0..1535
            int row = d / 6, c4 = d - row * 6;
            int drow = dir ? (SS - 1 - row) : row;
            dA[drow * 6 + c4] = srcA[d];
            dB[drow * 6 + c4] = srcB[d];
        }
        for (int g2 = lane; g2 < 8 * G4; g2 += 64) {
            sxgA[SS * G4 + g2] = 0.f;
            sxgB[SS * G4 + g2] = 0.f;
        }
    }

    int g    = lane % G4;                   // gate slot 0..23
    int cell = g >> 2;                      // 0..5
    int type = g & 3;                       // 0=i 1=f 2=c 3=o
    int j    = type * HH + cell;            // keras column

    float kk = (type == 2) ? 2.f * L2E : -L2E;
    float wh[HH];
    #pragma unroll
    for (int m = 0; m < HH; ++m) wh[m] = Wh[m * G4 + j] * kk;
    float Bc = (type == 2) ? 1.f : 0.f;
    float Ac = (type == 2) ? -1.f : 1.f;

    float shA[HH], shB[HH];
    #pragma unroll
    for (int m = 0; m < HH; ++m) { shA[m] = 0.f; shB[m] = 0.f; }
    float cA = 0.f, cB = 0.f;
    bool wr = (lane < G4) && ((lane & 3) == 0);
    __syncthreads();

    const float* xbA = sxgA + j;
    const float* xbB = sxgB + j;

    float pgA[4], pgB[4];
    #pragma unroll
    for (int sl = 0; sl < 4; ++sl) { pgA[sl] = xbA[sl * G4]; pgB[sl] = xbB[sl * G4]; }

    #pragma unroll 1
    for (int t = 0; t < SS; t += 4) {
        #pragma unroll
        for (int sl = 0; sl < 4; ++sl) {
            float x1 = pgA[sl], x2 = pgB[sl];
            pgA[sl] = xbA[(t + 4 + sl) * G4];    // guard rows cover the tail
            pgB[sl] = xbB[(t + 4 + sl) * G4];

            // dots (depth-4 trees), interleaved
            float a1 = fmaf(shA[1], wh[1], fmaf(shA[0], wh[0], x1));
            float a2 = fmaf(shB[1], wh[1], fmaf(shB[0], wh[0], x2));
            float b1 = fmaf(shA[3], wh[3], shA[2] * wh[2]);
            float b2 = fmaf(shB[3], wh[3], shB[2] * wh[2]);
            float d1 = fmaf(shA[5], wh[5], shA[4] * wh[4]);
            float d2 = fmaf(shB[5], wh[5], shB[4] * wh[4]);
            x1 = (a1 + b1) + d1;
            x2 = (a2 + b2) + d2;

            float e1 = __builtin_amdgcn_exp2f(x1);
            float e2 = __builtin_amdgcn_exp2f(x2);
            float v1 = fmaf(Bc, e1, Ac) * fast_rcp(1.f + e1);
            float v2 = fmaf(Bc, e2, Ac) * fast_rcp(1.f + e2);

            float vi1 = quad_bcast<0>(v1),   vi2 = quad_bcast<0>(v2);
            float vf1 = quad_bcast<85>(v1),  vf2 = quad_bcast<85>(v2);
            float vc1 = quad_bcast<170>(v1), vc2 = quad_bcast<170>(v2);
            float vo1 = quad_bcast<255>(v1), vo2 = quad_bcast<255>(v2);

            cA = fmaf(vf1, cA, vi1 * vc1);
            cB = fmaf(vf2, cB, vi2 * vc2);
            float ec1 = __builtin_amdgcn_exp2f(cA * (2.f * L2E));
            float ec2 = __builtin_amdgcn_exp2f(cB * (2.f * L2E));
            float h1 = (ec1 - 1.f) * fast_rcp(ec1 + 1.f) * vo1;
            float h2 = (ec2 - 1.f) * fast_rcp(ec2 + 1.f) * vo2;

            if (wr) {
                hbufA[(t + sl) * HH + cell] = h1;
                hbufB[(t + sl) * HH + cell] = h2;
            }
            #pragma unroll
            for (int m = 0; m < HH; ++m) {
                shA[m] = bcast_lane(h1, 4 * m);
                shB[m] = bcast_lane(h2, 4 * m);
            }
        }
    }
    __syncthreads();

    // coalesced copy out for both chains (undo time order for bwd)
    #pragma unroll
    for (int u = 0; u < (SS * HH) / 64; ++u) {
        int idx = lane + u * 64;
        int tt = idx / 6, cc = idx - tt * 6;
        int s = dir ? (SS - 1 - tt) : tt;
        repr[((size_t)bA * SS + s) * (2 * HH) + dir * HH + cc] = hbufA[idx];
        repr[((size_t)bB * SS + s) * (2 * HH) + dir * HH + cc] = hbufB[idx];
    }
}

// -------------------------------------------------------------------------
// Kernel 3: ua = repr@Wu+bu ; wa = repr@Ww+bw. One thread per (b,s).
// -------------------------------------------------------------------------
__global__ __launch_bounds__(256) void k_uawa(
    const float* __restrict__ repr,
    const float* __restrict__ Wu, const float* __restrict__ bu,
    const float* __restrict__ Ww, const float* __restrict__ bw,
    float* __restrict__ ua, float* __restrict__ wa)
{
    int bs = blockIdx.x * blockDim.x + threadIdx.x;   // 0..8191
    float r[AA];
    #pragma unroll
    for (int e = 0; e < AA; ++e) r[e] = repr[(size_t)bs * AA + e];
    #pragma unroll
    for (int d = 0; d < AA; ++d) {
        float au = bu[d], aw = bw[d];
        #pragma unroll
        for (int e = 0; e < AA; ++e) {
            au = fmaf(r[e], Wu[e * AA + d], au);
            aw = fmaf(r[e], Ww[e * AA + d], aw);
        }
        ua[(size_t)bs * AA + d] = au;
        wa[(size_t)bs * AA + d] = aw;
    }
}

// -------------------------------------------------------------------------
// Kernel 4: arc scores + sum-exp + CE partials + exp table.
// -------------------------------------------------------------------------
__global__ __launch_bounds__(256) void k_score(
    const float* __restrict__ ua, const float* __restrict__ wa,
    const float* __restrict__ v, const int* __restrict__ heads,
    float* __restrict__ out, float* __restrict__ ce)
{
    int bi = blockIdx.x;            // b*S + i
    int i  = bi & 255;
    int j  = threadIdx.x;

    __shared__ float swa[AA], sv[AA];
    if (j < AA) { swa[j] = wa[(size_t)bi * AA + j]; sv[j] = v[j]; }
    __syncthreads();

    const float* uj = ua + ((size_t)(bi & ~255) + j) * AA;
    float s = 0.f;
    #pragma unroll
    for (int d = 0; d < AA; ++d) s = fmaf(sv[d], fast_tanh(uj[d] + swa[d]), s);
    if (j == i) s = -10000.f;

    float e = __expf(s);
    if (i >= 1)
        out[1 + (((size_t)(i - 1) * BB + (bi >> 8)) * SS + j)] = e;

    float r = e;
    #pragma unroll
    for (int off = 32; off > 0; off >>= 1) r += __shfl_xor(r, off, 64);
    __shared__ float part[4];
    if ((j & 63) == 0) part[j >> 6] = r;
    __syncthreads();
    float tot = part[0] + part[1] + part[2] + part[3];

    if (j == heads[bi])
        ce[bi] = (i >= 1) ? (__logf(tot) - s) : 0.f;
}

// -------------------------------------------------------------------------
// Kernel 5: deterministic loss reduction: sum(ce)/B into out[0].
// -------------------------------------------------------------------------
__global__ __launch_bounds__(256) void k_loss(const float* __restrict__ ce,
                                              float* __restrict__ out)
{
    __shared__ float red[256];
    int t = threadIdx.x;
    float a = 0.f;
    for (int k = t; k < BB * SS; k += 256) a += ce[k];
    red[t] = a; __syncthreads();
    for (int off = 128; off > 0; off >>= 1) {
        if (t < off) red[t] += red[t + off];
        __syncthreads();
    }
    if (t == 0) out[0] = red[0] * (1.f / BB);
}

extern "C" void kernel_launch(void* const* d_in, const int* in_sizes, int n_in,
                              void* d_out, int out_size, void* d_ws, size_t ws_size,
                              hipStream_t stream)
{
    const int*   words = (const int*)  d_in[0];
    const int*   pos   = (const int*)  d_in[1];
    const float* morph = (const float*)d_in[2];
    const int*   heads = (const int*)  d_in[3];
    const float* wtab  = (const float*)d_in[4];
    const float* ptab  = (const float*)d_in[5];
    const float* Wxf   = (const float*)d_in[6];
    const float* Whf   = (const float*)d_in[7];
    const float* bf    = (const float*)d_in[8];
    const float* Wxb   = (const float*)d_in[9];
    const float* Whb   = (const float*)d_in[10];
    const float* bb    = (const float*)d_in[11];
    const float* Wu    = (const float*)d_in[12];
    const float* bu    = (const float*)d_in[13];
    const float* Ww    = (const float*)d_in[14];
    const float* bw    = (const float*)d_in[15];
    const float* v     = (const float*)d_in[16];
    float* out = (float*)d_out;

    // workspace layout (floats)
    float* xgf   = (float*)d_ws;                 // 8192*24 (prescaled)
    float* xgb   = xgf   + (size_t)BB*SS*G4;     // 8192*24 (prescaled)
    float* repr  = xgb   + (size_t)BB*SS*G4;     // 8192*12
    float* ua    = repr  + (size_t)BB*SS*2*HH;   // 8192*12
    float* wa    = ua    + (size_t)BB*SS*AA;     // 8192*12
    float* ce    = wa    + (size_t)BB*SS*AA;     // 8192

    k_embed_proj<<<(BB * SS) / EPB, 256, 0, stream>>>(words, pos, morph, wtab, ptab,
                                                      Wxf, bf, Wxb, bb, xgf, xgb);
    k_lstm<<<32, 64, 0, stream>>>(xgf, xgb, Whf, Whb, repr);
    k_uawa<<<(BB * SS) / 256, 256, 0, stream>>>(repr, Wu, bu, Ww, bw, ua, wa);
    k_score<<<BB * SS, 256, 0, stream>>>(ua, wa, v, heads, out, ce);
    k_loss<<<1, 256, 0, stream>>>(ce, out);
}

// Round 12
// 83.925 us; speedup vs baseline: 1.0806x; 1.0806x over previous
//
#include <hip/hip_runtime.h>
#include <hip/hip_bf16.h>

// Problem constants
#define BB 32
#define SS 256
#define DD 300
#define PDD 32
#define MM 66
#define FF 398      // D + PD + M
#define HH 6
#define G4 24       // 4*H
#define AA 12
#define L2E 1.4426950408889634f

__device__ __forceinline__ float fast_rcp(float x) { return __builtin_amdgcn_rcpf(x); }
__device__ __forceinline__ float bcast_lane(float x, int l) {
    return __int_as_float(__builtin_amdgcn_readlane(__float_as_int(x), l));
}
template<int CTRL>
__device__ __forceinline__ float quad_bcast(float v) {
    return __int_as_float(__builtin_amdgcn_mov_dpp(__float_as_int(v), CTRL, 0xf, 0xf, true));
}

// -------------------------------------------------------------------------
// Kernel 0: transpose Wx -> WT[dir][col][400] (k-contiguous, zero-padded)
// so k_xg can fetch W with wave-uniform scalar loads. Coalesced reads.
// -------------------------------------------------------------------------
__global__ __launch_bounds__(256) void k_wtprep(
    const float* __restrict__ Wxf, const float* __restrict__ Wxb,
    float* __restrict__ WT)
{
    const float* Wx = blockIdx.x ? Wxb : Wxf;
    float* wt = WT + blockIdx.x * (G4 * 400);
    int t = threadIdx.x;
    for (int idx = t; idx < FF * G4; idx += 256) {
        int k = idx / G4, j = idx % G4;
        wt[j * 400 + k] = Wx[idx];
    }
    if (t < 2 * G4) {                    // zero pad k = 398, 399
        int j = t >> 1, k = 398 + (t & 1);
        wt[j * 400 + k] = 0.f;
    }
}

// -------------------------------------------------------------------------
// Kernel 1 (v7): xg GEMM, W through the SCALAR pipe.
// Grid 128 (64 pos/block), 512 thr = 8 waves. Wave w: dir = w>>2, col-group
// tg = w&3 (keras cols tg*6..tg*6+5 = one gate type). W addresses are
// wave-uniform -> s_load_dwordx4; feats staged transposed in LDS. Hot loop
// per q: 1 ds_read_b128 + 24 fma. Epilogue folds bias + +-log2e prescale.
// -------------------------------------------------------------------------
__global__ __launch_bounds__(512) void k_xg(
    const int* __restrict__ words, const int* __restrict__ pos,
    const float* __restrict__ morph, const float* __restrict__ wtab,
    const float* __restrict__ ptab, const float* __restrict__ WT,
    const float* __restrict__ bfv, const float* __restrict__ bbv,
    float* __restrict__ xgf, float* __restrict__ xgb)
{
    __shared__ float4 sF[100][64];       // 102.4 KB: sF[q][p] = feats[p][4q..4q+3]
    int t  = threadIdx.x;
    int p0 = blockIdx.x * 64;

    // word part: q 0..74 (each lane one 16B granule from its word row)
    for (int idx = t; idx < 64 * 75; idx += 512) {
        int p = idx & 63, q = idx >> 6;
        sF[q][p] = *(const float4*)(wtab + (size_t)words[p0 + p] * DD + 4 * q);
    }
    // pos part: q 75..82 (512 = 64*8 exactly)
    {
        int p = t & 63, q = t >> 6;
        sF[75 + q][p] = *(const float4*)(ptab + pos[p0 + p] * PDD + 4 * q);
    }
    // morph part: q 83..99, float2 granularity (m 0..33; m=33 is zero pad)
    for (int idx = t; idx < 64 * 34; idx += 512) {
        int p = idx & 63, m = idx >> 6;
        const float2* ms = (const float2*)(morph + (size_t)(p0 + p) * MM);
        float2 v = (m < 33) ? ms[m] : make_float2(0.f, 0.f);
        ((float2*)&sF[83 + (m >> 1)][p])[m & 1] = v;
    }
    __syncthreads();

    int lane = t & 63;
    int w    = __builtin_amdgcn_readfirstlane(t >> 6);   // 0..7 wave-uniform
    int dir  = w >> 2;
    int tg   = w & 3;
    int j0   = tg * 6;
    const float* wb = WT + (dir * G4 + j0) * 400;

    float a0 = 0.f, a1 = 0.f, a2 = 0.f, a3 = 0.f, a4 = 0.f, a5 = 0.f;
    #pragma unroll 2
    for (int q = 0; q < 100; ++q) {
        float4 f  = sF[q][lane];
        const float4 w0 = *(const float4*)(wb + 0 * 400 + 4 * q);
        const float4 w1 = *(const float4*)(wb + 1 * 400 + 4 * q);
        const float4 w2 = *(const float4*)(wb + 2 * 400 + 4 * q);
        const float4 w3 = *(const float4*)(wb + 3 * 400 + 4 * q);
        const float4 w4 = *(const float4*)(wb + 4 * 400 + 4 * q);
        const float4 w5 = *(const float4*)(wb + 5 * 400 + 4 * q);
        a0 = fmaf(f.x, w0.x, a0); a0 = fmaf(f.y, w0.y, a0);
        a0 = fmaf(f.z, w0.z, a0); a0 = fmaf(f.w, w0.w, a0);
        a1 = fmaf(f.x, w1.x, a1); a1 = fmaf(f.y, w1.y, a1);
        a1 = fmaf(f.z, w1.z, a1); a1 = fmaf(f.w, w1.w, a1);
        a2 = fmaf(f.x, w2.x, a2); a2 = fmaf(f.y, w2.y, a2);
        a2 = fmaf(f.z, w2.z, a2); a2 = fmaf(f.w, w2.w, a2);
        a3 = fmaf(f.x, w3.x, a3); a3 = fmaf(f.y, w3.y, a3);
        a3 = fmaf(f.z, w3.z, a3); a3 = fmaf(f.w, w3.w, a3);
        a4 = fmaf(f.x, w4.x, a4); a4 = fmaf(f.y, w4.y, a4);
        a4 = fmaf(f.z, w4.z, a4); a4 = fmaf(f.w, w4.w, a4);
        a5 = fmaf(f.x, w5.x, a5); a5 = fmaf(f.y, w5.y, a5);
        a5 = fmaf(f.z, w5.z, a5); a5 = fmaf(f.w, w5.w, a5);
    }

    float kk = (tg == 2) ? 2.f * L2E : -L2E;     // wave-uniform gate prescale
    const float* bias = dir ? bbv : bfv;
    float* o = (dir ? xgb : xgf) + (size_t)(p0 + lane) * G4 + j0;
    ((float2*)o)[0] = make_float2((a0 + bias[j0 + 0]) * kk, (a1 + bias[j0 + 1]) * kk);
    ((float2*)o)[1] = make_float2((a2 + bias[j0 + 2]) * kk, (a3 + bias[j0 + 3]) * kk);
    ((float2*)o)[2] = make_float2((a4 + bias[j0 + 4]) * kk, (a5 + bias[j0 + 5]) * kk);
}

// -------------------------------------------------------------------------
// Kernel 2 (v9, unchanged from R9): LSTM recurrence, gate-lane + DPP.
// xg arrives pre-scaled; staging is a pure float4 copy (reversed for bwd).
// -------------------------------------------------------------------------
__global__ __launch_bounds__(64) void k_lstm(
    const float* __restrict__ xgf, const float* __restrict__ xgb,
    const float* __restrict__ Whf, const float* __restrict__ Whb,
    float* __restrict__ repr)
{
    __shared__ float sxg[(SS + 8) * G4];    // 8 zero guard rows
    __shared__ float hbuf[SS * HH];
    int blk = blockIdx.x;                   // 0..63
    int dir = blk >> 5;
    int b   = blk & 31;
    int lane = threadIdx.x;

    const float* xg = (dir ? xgb : xgf) + (size_t)b * SS * G4;
    const float* Wh = dir ? Whb : Whf;

    {
        const float4* src = (const float4*)xg;
        float4* dst = (float4*)sxg;
        #pragma unroll
        for (int u = 0; u < 24; ++u) {
            int d = lane + u * 64;          // float4 index 0..1535
            int row = d / 6, c4 = d - row * 6;
            int drow = dir ? (SS - 1 - row) : row;
            dst[drow * 6 + c4] = src[d];
        }
        for (int g2 = lane; g2 < 8 * G4; g2 += 64) sxg[SS * G4 + g2] = 0.f;
    }

    int g    = lane % G4;                   // gate slot 0..23
    int cell = g >> 2;                      // 0..5
    int type = g & 3;                       // 0=i 1=f 2=c 3=o
    int j    = type * HH + cell;            // keras column

    float kk = (type == 2) ? 2.f * L2E : -L2E;
    float wh[HH];
    #pragma unroll
    for (int m = 0; m < HH; ++m) wh[m] = Wh[m * G4 + j] * kk;
    float Bc = (type == 2) ? 1.f : 0.f;
    float Ac = (type == 2) ? -1.f : 1.f;

    float sh[HH];
    #pragma unroll
    for (int m = 0; m < HH; ++m) sh[m] = 0.f;
    float c = 0.f;
    bool wr = (lane < G4) && ((lane & 3) == 0);
    __syncthreads();

    const float* xb = sxg + j;

    float pg[4];
    #pragma unroll
    for (int sl = 0; sl < 4; ++sl) pg[sl] = xb[sl * G4];

    #pragma unroll 1
    for (int t = 0; t < SS; t += 4) {
        #pragma unroll
        for (int sl = 0; sl < 4; ++sl) {
            float x = pg[sl];
            pg[sl] = xb[(t + 4 + sl) * G4];      // guard rows cover the tail

            float aa  = fmaf(sh[1], wh[1], fmaf(sh[0], wh[0], x));
            float bb2 = fmaf(sh[3], wh[3], sh[2] * wh[2]);
            float cc2 = fmaf(sh[5], wh[5], sh[4] * wh[4]);
            x = (aa + bb2) + cc2;

            float e   = __builtin_amdgcn_exp2f(x);
            float val = fmaf(Bc, e, Ac) * fast_rcp(1.f + e);

            float vi = quad_bcast<0>(val);
            float vf = quad_bcast<85>(val);
            float vc = quad_bcast<170>(val);
            float vo = quad_bcast<255>(val);

            c = fmaf(vf, c, vi * vc);
            float ec = __builtin_amdgcn_exp2f(c * (2.f * L2E));
            float h  = (ec - 1.f) * fast_rcp(ec + 1.f) * vo;

            if (wr) hbuf[(t + sl) * HH + cell] = h;
            #pragma unroll
            for (int m = 0; m < HH; ++m) sh[m] = bcast_lane(h, 4 * m);
        }
    }
    __syncthreads();

    #pragma unroll
    for (int u = 0; u < (SS * HH) / 64; ++u) {
        int idx = lane + u * 64;
        int tt = idx / 6, cc = idx - tt * 6;
        int s = dir ? (SS - 1 - tt) : tt;
        repr[((size_t)b * SS + s) * (2 * HH) + dir * HH + cc] = hbuf[idx];
    }
}

// -------------------------------------------------------------------------
// Kernel 3: ua/wa = (repr@W + b) * 2log2e (prescaled for k_score's exp2).
// -------------------------------------------------------------------------
__global__ __launch_bounds__(256) void k_uawa(
    const float* __restrict__ repr,
    const float* __restrict__ Wu, const float* __restrict__ bu,
    const float* __restrict__ Ww, const float* __restrict__ bw,
    float* __restrict__ ua, float* __restrict__ wa)
{
    int bs = blockIdx.x * blockDim.x + threadIdx.x;   // 0..8191
    float r[AA];
    #pragma unroll
    for (int e = 0; e < AA; ++e) r[e] = repr[(size_t)bs * AA + e];
    #pragma unroll
    for (int d = 0; d < AA; ++d) {
        float au = bu[d], aw = bw[d];
        #pragma unroll
        for (int e = 0; e < AA; ++e) {
            au = fmaf(r[e], Wu[e * AA + d], au);
            aw = fmaf(r[e], Ww[e * AA + d], aw);
        }
        ua[(size_t)bs * AA + d] = au * (2.f * L2E);
        wa[(size_t)bs * AA + d] = aw * (2.f * L2E);
    }
}

// -------------------------------------------------------------------------
// Kernel 4: arc scores + sum-exp + CE partials + exp table.
// ua/wa prescaled by 2log2e: tanh(u+w) = 1 - 2*rcp(1+exp2(ua'+wa')), so
// s = sumv - 2*sum_d v_d * r_d  (5 ops/d instead of 7).
// -------------------------------------------------------------------------
__global__ __launch_bounds__(256) void k_score(
    const float* __restrict__ ua, const float* __restrict__ wa,
    const float* __restrict__ v, const int* __restrict__ heads,
    float* __restrict__ out, float* __restrict__ ce)
{
    int bi = blockIdx.x;            // b*S + i
    int i  = bi & 255;
    int j  = threadIdx.x;

    __shared__ float swa[AA], sv[AA];
    if (j < AA) { swa[j] = wa[(size_t)bi * AA + j]; sv[j] = v[j]; }
    __syncthreads();

    float sumv = 0.f;
    #pragma unroll
    for (int d = 0; d < AA; ++d) sumv += sv[d];

    const float* uj = ua + ((size_t)(bi & ~255) + j) * AA;
    float4 u0 = *(const float4*)(uj);
    float4 u1 = *(const float4*)(uj + 4);
    float4 u2 = *(const float4*)(uj + 8);
    float us[AA] = {u0.x, u0.y, u0.z, u0.w, u1.x, u1.y, u1.z, u1.w,
                    u2.x, u2.y, u2.z, u2.w};
    float acc = 0.f;
    #pragma unroll
    for (int d = 0; d < AA; ++d) {
        float e_d = __builtin_amdgcn_exp2f(us[d] + swa[d]);
        acc = fmaf(sv[d], fast_rcp(1.f + e_d), acc);
    }
    float s = fmaf(-2.f, acc, sumv);
    if (j == i) s = -10000.f;

    float e = __builtin_amdgcn_exp2f(s * L2E);
    if (i >= 1)
        out[1 + (((size_t)(i - 1) * BB + (bi >> 8)) * SS + j)] = e;

    float r = e;
    #pragma unroll
    for (int off = 32; off > 0; off >>= 1) r += __shfl_xor(r, off, 64);
    __shared__ float part[4];
    if ((j & 63) == 0) part[j >> 6] = r;
    __syncthreads();
    float tot = part[0] + part[1] + part[2] + part[3];

    if (j == heads[bi])
        ce[bi] = (i >= 1) ? (__logf(tot) - s) : 0.f;
}

// -------------------------------------------------------------------------
// Kernel 5: deterministic loss reduction: sum(ce)/B into out[0].
// -------------------------------------------------------------------------
__global__ __launch_bounds__(256) void k_loss(const float* __restrict__ ce,
                                              float* __restrict__ out)
{
    __shared__ float red[256];
    int t = threadIdx.x;
    float a = 0.f;
    for (int k = t; k < BB * SS; k += 256) a += ce[k];
    red[t] = a; __syncthreads();
    for (int off = 128; off > 0; off >>= 1) {
        if (t < off) red[t] += red[t + off];
        __syncthreads();
    }
    if (t == 0) out[0] = red[0] * (1.f / BB);
}

extern "C" void kernel_launch(void* const* d_in, const int* in_sizes, int n_in,
                              void* d_out, int out_size, void* d_ws, size_t ws_size,
                              hipStream_t stream)
{
    const int*   words = (const int*)  d_in[0];
    const int*   pos   = (const int*)  d_in[1];
    const float* morph = (const float*)d_in[2];
    const int*   heads = (const int*)  d_in[3];
    const float* wtab  = (const float*)d_in[4];
    const float* ptab  = (const float*)d_in[5];
    const float* Wxf   = (const float*)d_in[6];
    const float* Whf   = (const float*)d_in[7];
    const float* bf    = (const float*)d_in[8];
    const float* Wxb   = (const float*)d_in[9];
    const float* Whb   = (const float*)d_in[10];
    const float* bb    = (const float*)d_in[11];
    const float* Wu    = (const float*)d_in[12];
    const float* bu    = (const float*)d_in[13];
    const float* Ww    = (const float*)d_in[14];
    const float* bw    = (const float*)d_in[15];
    const float* v     = (const float*)d_in[16];
    float* out = (float*)d_out;

    // workspace layout (floats)
    float* xgf  = (float*)d_ws;                  // 8192*24 (prescaled)
    float* xgb  = xgf  + (size_t)BB*SS*G4;       // 8192*24 (prescaled)
    float* repr = xgb  + (size_t)BB*SS*G4;       // 8192*12
    float* ua   = repr + (size_t)BB*SS*2*HH;     // 8192*12 (prescaled 2log2e)
    float* wa   = ua   + (size_t)BB*SS*AA;       // 8192*12 (prescaled 2log2e)
    float* ce   = wa   + (size_t)BB*SS*AA;       // 8192
    float* WT   = ce   + (size_t)BB*SS;          // 2*24*400

    k_wtprep<<<2, 256, 0, stream>>>(Wxf, Wxb, WT);
    k_xg<<<(BB * SS) / 64, 512, 0, stream>>>(words, pos, morph, wtab, ptab, WT,
                                             bf, bb, xgf, xgb);
    k_lstm<<<BB * 2, 64, 0, stream>>>(xgf, xgb, Whf, Whb, repr);
    k_uawa<<<(BB * SS) / 256, 256, 0, stream>>>(repr, Wu, bu, Ww, bw, ua, wa);
    k_score<<<BB * SS, 256, 0, stream>>>(ua, wa, v, heads, out, ce);
    k_loss<<<1, 256, 0, stream>>>(ce, out);
}

// Round 13
// 74.151 us; speedup vs baseline: 1.2230x; 1.1318x over previous
//
#include <hip/hip_runtime.h>
#include <hip/hip_bf16.h>

// Problem constants
#define BB 32
#define SS 256
#define DD 300
#define PDD 32
#define MM 66
#define FF 398      // D + PD + M
#define HH 6
#define G4 24       // 4*H
#define AA 12
#define L2E 1.4426950408889634f

__device__ __forceinline__ float fast_rcp(float x) { return __builtin_amdgcn_rcpf(x); }
__device__ __forceinline__ float fast_tanh(float x) {
    return 1.f - 2.f * fast_rcp(__expf(2.f * x) + 1.f);
}
__device__ __forceinline__ float bcast_lane(float x, int l) {
    return __int_as_float(__builtin_amdgcn_readlane(__float_as_int(x), l));
}
template<int CTRL>
__device__ __forceinline__ float quad_bcast(float v) {
    return __int_as_float(__builtin_amdgcn_mov_dpp(__float_as_int(v), CTRL, 0xf, 0xf, true));
}

// -------------------------------------------------------------------------
// Kernel 1 (v5, R9-verbatim): fused embed+concat+projection.
// Block = 32 positions, 256 thr, grid 256 (1 block/CU). Feats transposed in
// LDS; all of W in LDS. Epilogue folds bias + the lstm's +-log2e prescale.
// -------------------------------------------------------------------------
#define EPB 32
__global__ __launch_bounds__(256) void k_embed_proj(
    const int* __restrict__ words, const int* __restrict__ pos,
    const float* __restrict__ morph, const float* __restrict__ wtab,
    const float* __restrict__ ptab,
    const float* __restrict__ Wxf, const float* __restrict__ bfv,
    const float* __restrict__ Wxb, const float* __restrict__ bbv,
    float* __restrict__ xgf, float* __restrict__ xgb)
{
    __shared__ float4 sF[100][33];      // 52.8 KB
    __shared__ float4 sW[48 * 100];     // 76.8 KB
    int t  = threadIdx.x;
    int p0 = blockIdx.x * EPB;

    for (int idx = t; idx < EPB * 75; idx += 256) {
        int p = idx / 75, q = idx % 75;
        sF[q][p] = *(const float4*)(wtab + (size_t)words[p0 + p] * DD + 4 * q);
    }
    {
        int idx = t;                    // EPB*8 = 256 exactly
        int p = idx / 8, q = idx % 8;
        sF[75 + q][p] = *(const float4*)(ptab + pos[p0 + p] * PDD + 4 * q);
    }
    for (int idx = t; idx < EPB * 17; idx += 256) {
        int p = idx / 17, mq = idx % 17;
        const float2* ms = (const float2*)(morph + (size_t)(p0 + p) * MM);
        float2 lo = ms[2 * mq];
        float2 hi = (mq < 16) ? ms[2 * mq + 1] : make_float2(0.f, 0.f);
        sF[83 + mq][p] = make_float4(lo.x, lo.y, hi.x, hi.y);
    }
    {
        float* sWf = (float*)sW;
        for (int idx = t; idx < FF * G4; idx += 256) {
            int k = idx / G4, j = idx % G4;
            sWf[j * 400 + k]        = Wxf[idx];
            sWf[(24 + j) * 400 + k] = Wxb[idx];
        }
        if (t < 2 * G4) {
            int j = t >> 1, k = 398 + (t & 1);
            sWf[j * 400 + k] = 0.f; sWf[(24 + j) * 400 + k] = 0.f;
        }
    }
    __syncthreads();

    int lane = t & 63, w = t >> 6;
    int p    = lane & 31;
    int cg   = w * 2 + (lane >> 5);
    int dir  = cg >> 2;
    int tg   = cg & 3;
    int j0   = tg * 6;
    const float4* wc = sW + (dir * 24 + j0) * 100;

    float a0 = 0.f, a1 = 0.f, a2 = 0.f, a3 = 0.f, a4 = 0.f, a5 = 0.f;
    #pragma unroll 4
    for (int q = 0; q < 100; ++q) {
        float4 f = sF[q][p];
        float4 w0 = wc[0 * 100 + q], w1 = wc[1 * 100 + q], w2 = wc[2 * 100 + q];
        float4 w3 = wc[3 * 100 + q], w4 = wc[4 * 100 + q], w5 = wc[5 * 100 + q];
        a0 = fmaf(f.x, w0.x, a0); a0 = fmaf(f.y, w0.y, a0);
        a0 = fmaf(f.z, w0.z, a0); a0 = fmaf(f.w, w0.w, a0);
        a1 = fmaf(f.x, w1.x, a1); a1 = fmaf(f.y, w1.y, a1);
        a1 = fmaf(f.z, w1.z, a1); a1 = fmaf(f.w, w1.w, a1);
        a2 = fmaf(f.x, w2.x, a2); a2 = fmaf(f.y, w2.y, a2);
        a2 = fmaf(f.z, w2.z, a2); a2 = fmaf(f.w, w2.w, a2);
        a3 = fmaf(f.x, w3.x, a3); a3 = fmaf(f.y, w3.y, a3);
        a3 = fmaf(f.z, w3.z, a3); a3 = fmaf(f.w, w3.w, a3);
        a4 = fmaf(f.x, w4.x, a4); a4 = fmaf(f.y, w4.y, a4);
        a4 = fmaf(f.z, w4.z, a4); a4 = fmaf(f.w, w4.w, a4);
        a5 = fmaf(f.x, w5.x, a5); a5 = fmaf(f.y, w5.y, a5);
        a5 = fmaf(f.z, w5.z, a5); a5 = fmaf(f.w, w5.w, a5);
    }

    float kk = (tg == 2) ? 2.f * L2E : -L2E;
    const float* bias = dir ? bbv : bfv;
    float* o = (dir ? xgb : xgf) + (size_t)(p0 + p) * G4 + j0;
    o[0] = (a0 + bias[j0 + 0]) * kk; o[1] = (a1 + bias[j0 + 1]) * kk;
    o[2] = (a2 + bias[j0 + 2]) * kk; o[3] = (a3 + bias[j0 + 3]) * kk;
    o[4] = (a4 + bias[j0 + 4]) * kk; o[5] = (a5 + bias[j0 + 5]) * kk;
}

// -------------------------------------------------------------------------
// Kernel 2 (v12): LSTM + uawa fused. Block = one batch b, 128 thr = 2 waves;
// wave 0 runs the fwd chain, wave 1 the bwd chain (separate SIMDs -> both
// chains at full latency in parallel, unlike in-wave interleave). Each wave
// is R9's v9 gate-lane/DPP chain verbatim. After syncthreads the block holds
// the batch's full repr in LDS -> compute ua/wa in-block (kills the k_uawa
// dispatch, its launch gap, and the repr global round-trip).
// -------------------------------------------------------------------------
__global__ __launch_bounds__(128) void k_lstm_uawa(
    const float* __restrict__ xgf, const float* __restrict__ xgb,
    const float* __restrict__ Whf, const float* __restrict__ Whb,
    const float* __restrict__ Wu, const float* __restrict__ bu,
    const float* __restrict__ Ww, const float* __restrict__ bw,
    float* __restrict__ ua, float* __restrict__ wa)
{
    __shared__ float sxg[2][(SS + 8) * G4];   // 50.7 KB (8 zero guard rows each)
    __shared__ float hbuf[2][SS * HH];        // 12 KB; [dir][chain-time*6+cell]
    int b    = blockIdx.x;                    // 0..31
    int lane = threadIdx.x & 63;
    int dir  = __builtin_amdgcn_readfirstlane(threadIdx.x >> 6);

    const float* xg = (dir ? xgb : xgf) + (size_t)b * SS * G4;
    const float* Wh = dir ? Whb : Whf;

    // stage this wave's xg -> LDS (pure copy; reverse rows for bwd)
    {
        const float4* src = (const float4*)xg;
        float4* dst = (float4*)sxg[dir];
        #pragma unroll
        for (int u = 0; u < 24; ++u) {
            int d = lane + u * 64;            // float4 index 0..1535
            int row = d / 6, c4 = d - row * 6;
            int drow = dir ? (SS - 1 - row) : row;
            dst[drow * 6 + c4] = src[d];
        }
        for (int g2 = lane; g2 < 8 * G4; g2 += 64) sxg[dir][SS * G4 + g2] = 0.f;
    }

    int g    = lane % G4;                   // gate slot 0..23
    int cell = g >> 2;                      // 0..5
    int type = g & 3;                       // 0=i 1=f 2=c 3=o
    int j    = type * HH + cell;            // keras column

    float kk = (type == 2) ? 2.f * L2E : -L2E;
    float wh[HH];
    #pragma unroll
    for (int m = 0; m < HH; ++m) wh[m] = Wh[m * G4 + j] * kk;
    float Bc = (type == 2) ? 1.f : 0.f;
    float Ac = (type == 2) ? -1.f : 1.f;

    float sh[HH];
    #pragma unroll
    for (int m = 0; m < HH; ++m) sh[m] = 0.f;
    float c = 0.f;
    bool wr = (lane < G4) && ((lane & 3) == 0);

    const float* xb = sxg[dir] + j;
    float* hb = hbuf[dir];

    // no barrier needed before the loop: each wave reads only its own slice
    float pg[4];
    #pragma unroll
    for (int sl = 0; sl < 4; ++sl) pg[sl] = xb[sl * G4];

    #pragma unroll 1
    for (int t = 0; t < SS; t += 4) {
        #pragma unroll
        for (int sl = 0; sl < 4; ++sl) {
            float x = pg[sl];
            pg[sl] = xb[(t + 4 + sl) * G4];      // guard rows cover the tail

            float aa  = fmaf(sh[1], wh[1], fmaf(sh[0], wh[0], x));
            float bb2 = fmaf(sh[3], wh[3], sh[2] * wh[2]);
            float cc2 = fmaf(sh[5], wh[5], sh[4] * wh[4]);
            x = (aa + bb2) + cc2;

            float e   = __builtin_amdgcn_exp2f(x);
            float val = fmaf(Bc, e, Ac) * fast_rcp(1.f + e);

            float vi = quad_bcast<0>(val);
            float vf = quad_bcast<85>(val);
            float vc = quad_bcast<170>(val);
            float vo = quad_bcast<255>(val);

            c = fmaf(vf, c, vi * vc);
            float ec = __builtin_amdgcn_exp2f(c * (2.f * L2E));
            float h  = (ec - 1.f) * fast_rcp(ec + 1.f) * vo;

            if (wr) hb[(t + sl) * HH + cell] = h;
            #pragma unroll
            for (int m = 0; m < HH; ++m) sh[m] = bcast_lane(h, 4 * m);
        }
    }
    __syncthreads();

    // epilogue: ua/wa for this batch's 256 positions (2 per thread).
    // repr[s] = [ hf[s] = hbuf[0][s*6+c] , hb[s] = hbuf[1][(SS-1-s)*6+c] ]
    #pragma unroll
    for (int half = 0; half < 2; ++half) {
        int s = (int)threadIdx.x + half * 128;
        float r[AA];
        #pragma unroll
        for (int cc = 0; cc < HH; ++cc) {
            r[cc]      = hbuf[0][s * HH + cc];
            r[HH + cc] = hbuf[1][(SS - 1 - s) * HH + cc];
        }
        float au[AA], aw[AA];
        #pragma unroll
        for (int d = 0; d < AA; ++d) { au[d] = bu[d]; aw[d] = bw[d]; }
        #pragma unroll
        for (int e2 = 0; e2 < AA; ++e2) {
            #pragma unroll
            for (int d = 0; d < AA; ++d) {
                au[d] = fmaf(r[e2], Wu[e2 * AA + d], au[d]);
                aw[d] = fmaf(r[e2], Ww[e2 * AA + d], aw[d]);
            }
        }
        float* ou = ua + ((size_t)b * SS + s) * AA;
        float* ow = wa + ((size_t)b * SS + s) * AA;
        #pragma unroll
        for (int d4 = 0; d4 < 3; ++d4) {
            *(float4*)(ou + 4 * d4) = make_float4(au[4*d4], au[4*d4+1], au[4*d4+2], au[4*d4+3]);
            *(float4*)(ow + 4 * d4) = make_float4(aw[4*d4], aw[4*d4+1], aw[4*d4+2], aw[4*d4+3]);
        }
    }
}

// -------------------------------------------------------------------------
// Kernel 4 (R9-verbatim): arc scores + sum-exp + CE partials + exp table.
// -------------------------------------------------------------------------
__global__ __launch_bounds__(256) void k_score(
    const float* __restrict__ ua, const float* __restrict__ wa,
    const float* __restrict__ v, const int* __restrict__ heads,
    float* __restrict__ out, float* __restrict__ ce)
{
    int bi = blockIdx.x;            // b*S + i
    int i  = bi & 255;
    int j  = threadIdx.x;

    __shared__ float swa[AA], sv[AA];
    if (j < AA) { swa[j] = wa[(size_t)bi * AA + j]; sv[j] = v[j]; }
    __syncthreads();

    const float* uj = ua + ((size_t)(bi & ~255) + j) * AA;
    float s = 0.f;
    #pragma unroll
    for (int d = 0; d < AA; ++d) s = fmaf(sv[d], fast_tanh(uj[d] + swa[d]), s);
    if (j == i) s = -10000.f;

    float e = __expf(s);
    if (i >= 1)
        out[1 + (((size_t)(i - 1) * BB + (bi >> 8)) * SS + j)] = e;

    float r = e;
    #pragma unroll
    for (int off = 32; off > 0; off >>= 1) r += __shfl_xor(r, off, 64);
    __shared__ float part[4];
    if ((j & 63) == 0) part[j >> 6] = r;
    __syncthreads();
    float tot = part[0] + part[1] + part[2] + part[3];

    if (j == heads[bi])
        ce[bi] = (i >= 1) ? (__logf(tot) - s) : 0.f;
}

// -------------------------------------------------------------------------
// Kernel 5 (R9-verbatim): deterministic loss reduction: sum(ce)/B -> out[0].
// -------------------------------------------------------------------------
__global__ __launch_bounds__(256) void k_loss(const float* __restrict__ ce,
                                              float* __restrict__ out)
{
    __shared__ float red[256];
    int t = threadIdx.x;
    float a = 0.f;
    for (int k = t; k < BB * SS; k += 256) a += ce[k];
    red[t] = a; __syncthreads();
    for (int off = 128; off > 0; off >>= 1) {
        if (t < off) red[t] += red[t + off];
        __syncthreads();
    }
    if (t == 0) out[0] = red[0] * (1.f / BB);
}

extern "C" void kernel_launch(void* const* d_in, const int* in_sizes, int n_in,
                              void* d_out, int out_size, void* d_ws, size_t ws_size,
                              hipStream_t stream)
{
    const int*   words = (const int*)  d_in[0];
    const int*   pos   = (const int*)  d_in[1];
    const float* morph = (const float*)d_in[2];
    const int*   heads = (const int*)  d_in[3];
    const float* wtab  = (const float*)d_in[4];
    const float* ptab  = (const float*)d_in[5];
    const float* Wxf   = (const float*)d_in[6];
    const float* Whf   = (const float*)d_in[7];
    const float* bf    = (const float*)d_in[8];
    const float* Wxb   = (const float*)d_in[9];
    const float* Whb   = (const float*)d_in[10];
    const float* bb    = (const float*)d_in[11];
    const float* Wu    = (const float*)d_in[12];
    const float* bu    = (const float*)d_in[13];
    const float* Ww    = (const float*)d_in[14];
    const float* bw    = (const float*)d_in[15];
    const float* v     = (const float*)d_in[16];
    float* out = (float*)d_out;

    // workspace layout (floats)
    float* xgf  = (float*)d_ws;                  // 8192*24 (prescaled)
    float* xgb  = xgf  + (size_t)BB*SS*G4;       // 8192*24 (prescaled)
    float* ua   = xgb  + (size_t)BB*SS*G4;       // 8192*12
    float* wa   = ua   + (size_t)BB*SS*AA;       // 8192*12
    float* ce   = wa   + (size_t)BB*SS*AA;       // 8192

    k_embed_proj<<<(BB * SS) / EPB, 256, 0, stream>>>(words, pos, morph, wtab, ptab,
                                                      Wxf, bf, Wxb, bb, xgf, xgb);
    k_lstm_uawa<<<BB, 128, 0, stream>>>(xgf, xgb, Whf, Whb, Wu, bu, Ww, bw, ua, wa);
    k_score<<<BB * SS, 256, 0, stream>>>(ua, wa, v, heads, out, ce);
    k_loss<<<1, 256, 0, stream>>>(ce, out);
}